// Round 9
// baseline (1924.342 us; speedup 1.0000x reference)
//
#include <hip/hip_runtime.h>
#include <hip/hip_bf16.h>

// Problem constants (Mixtral attention prefill)
#define S_LEN 2048
#define HID 4096
#define NH 32
#define NKV 8
#define HD 128
#define NQKV 6144   // NH*HD + 2*NKV*HD

typedef unsigned short u16;
typedef unsigned int u32;
typedef __bf16 bf16x8 __attribute__((ext_vector_type(8)));
typedef float f32x4 __attribute__((ext_vector_type(4)));

__device__ __forceinline__ float bf2f(u16 u) {
    union { u32 i; float f; } x; x.i = ((u32)u) << 16; return x.f;
}
__device__ __forceinline__ u16 f2bf(float f) {
    union { float f; u32 i; } x; x.f = f;
    u32 r = x.i + 0x7fffu + ((x.i >> 16) & 1u);   // RNE
    return (u16)(r >> 16);
}
__device__ __forceinline__ u32 pack2(float a, float b) {
    return (u32)f2bf(a) | ((u32)f2bf(b) << 16);
}
// async global->LDS, 16 B per lane; LDS dest is wave-uniform base + lane*16
__device__ __forceinline__ void gld16(const u16* g, u16* l) {
    __builtin_amdgcn_global_load_lds(
        (const __attribute__((address_space(1))) u32*)g,
        (__attribute__((address_space(3))) u32*)l, 16, 0, 0);
}

// ---------------------------------------------------------------------------
// fp32 -> bf16 convert (8 elems/thread), n8 = n/8
// ---------------------------------------------------------------------------
__global__ __launch_bounds__(256) void cvt_f32_bf16(
    const float* __restrict__ src, u16* __restrict__ dst, int n8)
{
    int i = blockIdx.x * 256 + threadIdx.x;
    if (i >= n8) return;
    const float4* s = (const float4*)src + (size_t)i * 2;
    float4 x0 = s[0], x1 = s[1];
    uint4 p;
    p.x = pack2(x0.x, x0.y); p.y = pack2(x0.z, x0.w);
    p.z = pack2(x1.x, x1.y); p.w = pack2(x1.z, x1.w);
    *((uint4*)dst + i) = p;
}

// ---------------------------------------------------------------------------
// All four pre-GEMM converts in ONE launch (h, wq, wk, wv).
// i-space: [0,1048576) h | [.,3145728) wq | [.,3670016) wk | [.,4194304) wv
// ---------------------------------------------------------------------------
__global__ __launch_bounds__(256) void cvt_all(
    const float* __restrict__ h, const float* __restrict__ wq,
    const float* __restrict__ wk, const float* __restrict__ wv,
    u16* __restrict__ hb, u16* __restrict__ wqkvb)
{
    int i = blockIdx.x * 256 + threadIdx.x;
    const float* src; u16* dst; int off;
    if (i < 1048576)      { src = h;  dst = hb;               off = i; }
    else if (i < 3145728) { src = wq; dst = wqkvb;            off = i - 1048576; }
    else if (i < 3670016) { src = wk; dst = wqkvb + 16777216; off = i - 3145728; }
    else                  { src = wv; dst = wqkvb + 20971520; off = i - 3670016; }
    const float4* s = (const float4*)src + (size_t)off * 2;
    float4 x0 = s[0], x1 = s[1];
    uint4 p;
    p.x = pack2(x0.x, x0.y); p.y = pack2(x0.z, x0.w);
    p.z = pack2(x1.x, x1.y); p.w = pack2(x1.z, x1.w);
    *((uint4*)dst + off) = p;
}

// ---------------------------------------------------------------------------
// m97-style GEMM: C[M][N] = X[M][K] * W[N][K]^T, all bf16, fp32 acc.
// 128x128 tile, BK=32, 4 waves in 2x2; 4x4 16x16 C-tiles per wave.
// T1: XCD-aware bijective block swizzle (grids here are %8==0).
// EPI: 0 = f32 C, 1 = bf16 C, 2 = fused RoPE->qb/kb/vb (head-major).
// R7: EPI==2 dumps each mt-round of acc to the dead As/Bs LDS; RoPE trig
//     runs on LDS data (acc's live range ends at the ds_write).
// R9 FIX (rule #20): the epilogue's mt loop MUST be #pragma unroll.
//     Without it, acc[mt][...] is a runtime index into an ext_vector
//     array -> the whole acc[4][4] is allocated in scratch for the entire
//     kernel -> every K-iteration spills (5.2 GB WRITE_SIZE, 10x slow).
// ---------------------------------------------------------------------------
template <int EPI>
__global__ __launch_bounds__(256) void gemm128(
    const u16* __restrict__ X, const u16* __restrict__ W,
    void* __restrict__ C, int K, int ldc,
    const int* __restrict__ pos,
    u16* __restrict__ qbO, u16* __restrict__ kbO, u16* __restrict__ vbO)
{
    __shared__ __align__(16) u16 smemU[128 * 32 * 2];   // 16 KB (As | Bs)
    u16* As = smemU;
    u16* Bs = smemU + 128 * 32;

    const int tid  = threadIdx.x;
    const int w    = tid >> 6;
    const int lane = tid & 63;
    const int quad = lane >> 4;
    const int n16  = lane & 15;

    int id = blockIdx.y * gridDim.x + blockIdx.x;
    const int nwg = gridDim.x * gridDim.y;
    if ((nwg & 7) == 0) {
        const int cpx = nwg >> 3;
        id = (id & 7) * cpx + (id >> 3);
    }
    const int m0 = (id / gridDim.x) * 128;
    const int n0 = (id % gridDim.x) * 128;

    const int wr = (w >> 1) * 64;
    const int wc = (w & 1) * 64;

    const int c0 = tid;          // staging chunk ids: row=c>>2, koff=(c&3)*8
    const int c1 = tid + 256;

    f32x4 acc[4][4] = {};

    for (int k0 = 0; k0 < K; k0 += 32) {
        __syncthreads();
        gld16(X + (size_t)(m0 + (c0 >> 2)) * K + k0 + (c0 & 3) * 8,
              As + (size_t)(w * 64) * 8);
        gld16(X + (size_t)(m0 + (c1 >> 2)) * K + k0 + (c1 & 3) * 8,
              As + (size_t)(256 + w * 64) * 8);
        gld16(W + (size_t)(n0 + (c0 >> 2)) * K + k0 + (c0 & 3) * 8,
              Bs + (size_t)(w * 64) * 8);
        gld16(W + (size_t)(n0 + (c1 >> 2)) * K + k0 + (c1 & 3) * 8,
              Bs + (size_t)(256 + w * 64) * 8);
        __syncthreads();

        bf16x8 a[4], b[4];
#pragma unroll
        for (int t = 0; t < 4; ++t) {
            a[t] = *reinterpret_cast<const bf16x8*>(As + (wr + t * 16 + n16) * 32 + quad * 8);
            b[t] = *reinterpret_cast<const bf16x8*>(Bs + (wc + t * 16 + n16) * 32 + quad * 8);
        }
#pragma unroll
        for (int mt = 0; mt < 4; ++mt)
#pragma unroll
            for (int nt = 0; nt < 4; ++nt)
                acc[mt][nt] = __builtin_amdgcn_mfma_f32_16x16x32_bf16(
                    a[mt], b[nt], acc[mt][nt], 0, 0, 0);
    }

    if constexpr (EPI == 2) {
        const int ht = n0 >> 7;               // head tile 0..47
        if (ht >= 40) {                       // ---- v: plain head-major store
            const int gg = ht - 40;
#pragma unroll
            for (int mt = 0; mt < 4; ++mt)
#pragma unroll
                for (int nt = 0; nt < 4; ++nt) {
                    const int col = wc + nt * 16 + n16;
#pragma unroll
                    for (int r = 0; r < 4; ++r) {
                        const int row = wr + mt * 16 + quad * 4 + r;
                        vbO[((size_t)gg * S_LEN + m0 + row) * HD + col] =
                            f2bf(acc[mt][nt][r]);
                    }
                }
            return;
        }
        // ---- q/k: RoPE via LDS round-trip (acc dies at the ds_write) ----
        u16* out = (ht < 32) ? qbO : kbO;
        const int hh = (ht < 32) ? ht : ht - 32;
        const float qs = (ht < 32) ? 0.08838834764831845f : 1.0f;
        float* smemF = reinterpret_cast<float*>(smemU);   // [32][128] f32
        const int wrg  = w >> 1;
        const int prow = tid >> 3;            // 0..31: smem row this thread reads
        const int pj   = (tid & 7) * 8;       // j0 in [0,64) step 8
        const int growB = m0 + (prow >> 4) * 64 + (prow & 15);

#pragma unroll
        for (int mt = 0; mt < 4; ++mt) {      // R9: MUST be unrolled (rule #20)
            __syncthreads();   // staging reads (mt=0) / prev round reads done
#pragma unroll
            for (int nt = 0; nt < 4; ++nt)
#pragma unroll
                for (int r = 0; r < 4; ++r)
                    smemF[(wrg * 16 + quad * 4 + r) * 128 + wc + nt * 16 + n16] =
                        acc[mt][nt][r];
            __syncthreads();

            const int grow = growB + mt * 16;
            const float p = (float)pos[grow];
            const size_t base = ((size_t)hh * S_LEN + grow) * HD;
            u16 lo[8], hi[8];
#pragma unroll
            for (int jj = 0; jj < 8; ++jj) {
                const int j = pj + jj;
                const float f  = p * exp2f(-0.31143075889569023f * (float)j);
                const float cv = cosf(f), sv = sinf(f);
                const float x1 = smemF[prow * 128 + j];
                const float x2 = smemF[prow * 128 + j + 64];
                lo[jj] = f2bf((x1 * cv - x2 * sv) * qs);
                hi[jj] = f2bf((x2 * cv + x1 * sv) * qs);
            }
            uint4 pl, ph;
            pl.x = (u32)lo[0] | ((u32)lo[1] << 16); pl.y = (u32)lo[2] | ((u32)lo[3] << 16);
            pl.z = (u32)lo[4] | ((u32)lo[5] << 16); pl.w = (u32)lo[6] | ((u32)lo[7] << 16);
            ph.x = (u32)hi[0] | ((u32)hi[1] << 16); ph.y = (u32)hi[2] | ((u32)hi[3] << 16);
            ph.z = (u32)hi[4] | ((u32)hi[5] << 16); ph.w = (u32)hi[6] | ((u32)hi[7] << 16);
            *reinterpret_cast<uint4*>(out + base + pj)      = pl;
            *reinterpret_cast<uint4*>(out + base + 64 + pj) = ph;
        }
        return;
    }

#pragma unroll
    for (int mt = 0; mt < 4; ++mt) {
        const int row0 = m0 + wr + mt * 16 + quad * 4;
#pragma unroll
        for (int nt = 0; nt < 4; ++nt) {
            const int col = n0 + wc + nt * 16 + n16;
#pragma unroll
            for (int r = 0; r < 4; ++r) {
                if constexpr (EPI == 1)
                    ((u16*)C)[(size_t)(row0 + r) * ldc + col] = f2bf(acc[mt][nt][r]);
                else
                    ((float*)C)[(size_t)(row0 + r) * ldc + col] = acc[mt][nt][r];
            }
        }
    }
}

// ---------------------------------------------------------------------------
// Fallback GEMM (R3): fp32 inputs converted on the fly, 64x64 tile.
// ---------------------------------------------------------------------------
template <bool XF32, bool OUTBF16>
__global__ __launch_bounds__(256) void gemm_bt(
    const void* __restrict__ Xv,
    const float* __restrict__ W0, int r1,
    const float* __restrict__ W1, int r2,
    const float* __restrict__ W2,
    void* __restrict__ C, int K, int ldc)
{
    __shared__ u16 Xs[64][48];
    __shared__ u16 Ws[64][48];

    const int tid  = threadIdx.x;
    const int w    = tid >> 6;
    const int lane = tid & 63;
    const int m0   = blockIdx.y * 64;
    const int n0   = blockIdx.x * 64;

    const int sr = tid >> 2;
    const int sc = (tid & 3) * 8;

    const float* xrow32 = nullptr;
    const u16*   xrow16 = nullptr;
    if constexpr (XF32) xrow32 = (const float*)Xv + (size_t)(m0 + sr) * K;
    else                xrow16 = (const u16*)Xv + (size_t)(m0 + sr) * K;

    const int wr = n0 + sr;
    const float* wrow;
    if (wr < r1)      wrow = W0 + (size_t)wr * K;
    else if (wr < r2) wrow = W1 + (size_t)(wr - r1) * K;
    else              wrow = W2 + (size_t)(wr - r2) * K;

    f32x4 acc[4] = {};
    const int mrow = w * 16 + (lane & 15);
    const int nrow = lane & 15;
    const int kq   = (lane >> 4) * 8;

    for (int k0 = 0; k0 < K; k0 += 32) {
        __syncthreads();
        if constexpr (XF32) {
            float4 x0 = *reinterpret_cast<const float4*>(xrow32 + k0 + sc);
            float4 x1 = *reinterpret_cast<const float4*>(xrow32 + k0 + sc + 4);
            uint4 p;
            p.x = pack2(x0.x, x0.y); p.y = pack2(x0.z, x0.w);
            p.z = pack2(x1.x, x1.y); p.w = pack2(x1.z, x1.w);
            *reinterpret_cast<uint4*>(&Xs[sr][sc]) = p;
        } else {
            *reinterpret_cast<uint4*>(&Xs[sr][sc]) =
                *reinterpret_cast<const uint4*>(xrow16 + k0 + sc);
        }
        {
            float4 w0v = *reinterpret_cast<const float4*>(wrow + k0 + sc);
            float4 w1v = *reinterpret_cast<const float4*>(wrow + k0 + sc + 4);
            uint4 p;
            p.x = pack2(w0v.x, w0v.y); p.y = pack2(w0v.z, w0v.w);
            p.z = pack2(w1v.x, w1v.y); p.w = pack2(w1v.z, w1v.w);
            *reinterpret_cast<uint4*>(&Ws[sr][sc]) = p;
        }
        __syncthreads();
        bf16x8 a = *reinterpret_cast<const bf16x8*>(&Xs[mrow][kq]);
#pragma unroll
        for (int t = 0; t < 4; ++t) {
            bf16x8 b = *reinterpret_cast<const bf16x8*>(&Ws[t * 16 + nrow][kq]);
            acc[t] = __builtin_amdgcn_mfma_f32_16x16x32_bf16(a, b, acc[t], 0, 0, 0);
        }
    }

    const int mb = m0 + w * 16 + ((lane >> 4) << 2);
#pragma unroll
    for (int t = 0; t < 4; ++t) {
        const int col = n0 + t * 16 + (lane & 15);
#pragma unroll
        for (int i = 0; i < 4; ++i) {
            if constexpr (OUTBF16)
                ((u16*)C)[(size_t)(mb + i) * ldc + col] = f2bf(acc[t][i]);
            else
                ((float*)C)[(size_t)(mb + i) * ldc + col] = acc[t][i];
        }
    }
}

// ---------------------------------------------------------------------------
// RoPE (half-split, theta=1e6); Q pre-scaled by 1/sqrt(HD).  (fallback only)
// ---------------------------------------------------------------------------
__global__ __launch_bounds__(256) void rope_kernel(
    const u16* __restrict__ qkv, const int* __restrict__ pos,
    u16* __restrict__ qb, u16* __restrict__ kb, u16* __restrict__ vb)
{
    const int n   = blockIdx.x;
    const int tid = threadIdx.x;
    const float scale = 0.08838834764831845f;
    __shared__ float cs[64], sn[64];
    if (tid < 64) {
        float p   = (float)pos[n];
        float inv = powf(1.0e6f, -(float)tid / 64.0f);
        float f   = p * inv;
        cs[tid] = cosf(f);
        sn[tid] = sinf(f);
    }
    __syncthreads();
    const u16* row = qkv + (size_t)n * NQKV;

    for (int i = tid; i < NH * 64; i += 256) {
        int h = i >> 6, j = i & 63;
        float x1 = bf2f(row[h * HD + j]), x2 = bf2f(row[h * HD + j + 64]);
        size_t base = ((size_t)h * S_LEN + n) * HD;
        qb[base + j]      = f2bf((x1 * cs[j] - x2 * sn[j]) * scale);
        qb[base + j + 64] = f2bf((x2 * cs[j] + x1 * sn[j]) * scale);
    }
    for (int i = tid; i < NKV * 64; i += 256) {
        int g = i >> 6, j = i & 63;
        const u16* kr = row + NH * HD + g * HD;
        float x1 = bf2f(kr[j]), x2 = bf2f(kr[j + 64]);
        size_t base = ((size_t)g * S_LEN + n) * HD;
        kb[base + j]      = f2bf(x1 * cs[j] - x2 * sn[j]);
        kb[base + j + 64] = f2bf(x2 * cs[j] + x1 * sn[j]);
    }
    for (int i = tid; i < NKV * HD; i += 256) {
        int g = i >> 7, d = i & 127;
        vb[((size_t)g * S_LEN + n) * HD + d] = row[NH * HD + NKV * HD + g * HD + d];
    }
}

// ---------------------------------------------------------------------------
// MFMA flash attention (causal GQA).
// R5: q-tile pairing (i, 31-i); R6: XOR-swizzled LDS, P aliases K buffer;
// R7: in-block split-K (8 waves, even/odd K-tiles); R8/R9: bounds (512,2),
// K via global_load_lds with pre-swizzled source (T21).
// ---------------------------------------------------------------------------
__global__ __launch_bounds__(512, 2) void attn_mfma(
    const u16* __restrict__ qb, const u16* __restrict__ kb,
    const u16* __restrict__ vb, u16* __restrict__ ao)
{
    // 64 KB: KP[2] (16 KB each; softmax P aliases low 8 KB), Vt[2] (16 KB each)
    __shared__ __align__(16) u16 smem[32768];

    const int tid  = threadIdx.x;
    const int gtid = tid & 255;        // id within group
    const int grp  = tid >> 8;         // 0: even tiles, 1: odd tiles
    const int wg   = (tid >> 6) & 3;   // wave within group
    const int lane = tid & 63;
    const int quad = lane >> 4;
    const int n16  = lane & 15;
    const int h    = blockIdx.y;
    const int g    = h >> 2;
    const int NQT  = S_LEN / 64;       // 32 q-tiles

    u16* KPg = smem + grp * 8192;            // 64 x 128 (stride 128)
    u16* Vtg = smem + 16384 + grp * 8192;    // 128 x 64 (stride 64)
    float* mrg = reinterpret_cast<float*>(smem);  // merge buffer (40 KB)

    const u16* kbase = kb + (size_t)g * S_LEN * HD;
    const u16* vbase = vb + (size_t)g * S_LEN * HD;
    const int xsw = (n16 & 7) << 3;   // read-side XOR swizzle (u16 units)

    // K staging: call i, chunk c = i*256 + gtid ->
    //   LDS row = i*16 + (gtid>>4), col = (gtid&15)*8 (linear dest);
    //   source col pre-swizzled so LDS[row][c] = K[row][c ^ ((row&7)<<3)].
    const int krow = gtid >> 4;                                // 0..15
    const int kcol = ((gtid & 15) ^ ((gtid >> 4) & 7)) << 3;   // pre-swizzled
    u16* kdst = KPg + (size_t)(wg * 64) * 8;                   // + i*256*8

    for (int half = 0; half < 2; ++half) {
        const int qt = half ? (NQT - 1 - blockIdx.x) : blockIdx.x;
        const int q0 = qt * 64;

        bf16x8 qf[4];
        {
            const u16* qrow = qb + ((size_t)h * S_LEN + q0 + wg * 16 + n16) * HD;
#pragma unroll
            for (int s = 0; s < 4; ++s)
                qf[s] = *reinterpret_cast<const bf16x8*>(qrow + s * 32 + quad * 8);
        }

        f32x4 of[8] = {};
        float mrow[4], lrow[4];
#pragma unroll
        for (int r = 0; r < 4; ++r) { mrow[r] = -1e30f; lrow[r] = 0.0f; }

        uint4 vreg[4];
        auto load_v = [&](int k0) {
#pragma unroll
            for (int i = 0; i < 4; ++i)
                vreg[i] = *reinterpret_cast<const uint4*>(
                    vbase + (size_t)(k0 + lane) * HD + wg * 8 + i * 32);
        };
        load_v(grp * 64);   // prologue: this group's first tile

        const int ntiles = qt + 1;
        const int nIt = (ntiles + 1) >> 1;
        for (int it = 0; it < nIt; ++it) {
            const int kt = 2 * it + grp;
            const bool act = (kt < ntiles);

            __syncthreads();   // prev tile's PV / merge reads done; LDS free
            if (act) {
                const int k0 = kt * 64;
#pragma unroll
                for (int i = 0; i < 4; ++i)
                    gld16(kbase + (size_t)(k0 + i * 16 + krow) * HD + kcol,
                          kdst + (size_t)(i * 256) * 8);
#pragma unroll
                for (int i = 0; i < 4; ++i) {
                    const int d0 = wg * 8 + i * 32;
                    const u32 vw[4] = {vreg[i].x, vreg[i].y, vreg[i].z, vreg[i].w};
#pragma unroll
                    for (int t = 0; t < 4; ++t) {
                        const int r0 = d0 + 2 * t;
                        Vtg[r0 * 64 + (lane ^ ((r0 & 7) << 3))]             = (u16)(vw[t] & 0xffff);
                        Vtg[(r0 + 1) * 64 + (lane ^ (((r0 + 1) & 7) << 3))] = (u16)(vw[t] >> 16);
                    }
                }
            }
            __syncthreads();   // staging visible
            if (kt + 2 < ntiles) load_v((kt + 2) * 64);

            f32x4 sc[4] = {};
            if (act) {
#pragma unroll
                for (int s = 0; s < 4; ++s) {
#pragma unroll
                    for (int t = 0; t < 4; ++t) {
                        bf16x8 bf = *reinterpret_cast<const bf16x8*>(
                            &KPg[(t * 16 + n16) * 128 + ((s * 32 + quad * 8) ^ xsw)]);
                        sc[t] = __builtin_amdgcn_mfma_f32_16x16x32_bf16(qf[s], bf, sc[t], 0, 0, 0);
                    }
                }
                if (kt == qt) {   // diagonal tile: causal mask
                    const int qbase = q0 + wg * 16 + quad * 4;
#pragma unroll
                    for (int t = 0; t < 4; ++t) {
                        int key = kt * 64 + t * 16 + n16;
#pragma unroll
                        for (int r = 0; r < 4; ++r)
                            if (key > qbase + r) sc[t][r] = -1e30f;
                    }
                }
            }

            __syncthreads();   // group's waves done reading K; P may overwrite

            if (act) {
#pragma unroll
                for (int r = 0; r < 4; ++r) {
                    float mx = fmaxf(fmaxf(sc[0][r], sc[1][r]), fmaxf(sc[2][r], sc[3][r]));
                    mx = fmaxf(mx, __shfl_xor(mx, 1));
                    mx = fmaxf(mx, __shfl_xor(mx, 2));
                    mx = fmaxf(mx, __shfl_xor(mx, 4));
                    mx = fmaxf(mx, __shfl_xor(mx, 8));
                    float mnew  = fmaxf(mrow[r], mx);
                    float alpha = __expf(mrow[r] - mnew);
                    float ls = 0.0f;
                    const int pr = quad * 4 + r;
#pragma unroll
                    for (int t = 0; t < 4; ++t) {
                        float p = __expf(sc[t][r] - mnew);
                        KPg[(wg * 16 + pr) * 64 + ((t * 16 + n16) ^ ((pr & 7) << 3))] = f2bf(p);
                        ls += p;
                    }
                    ls += __shfl_xor(ls, 1);
                    ls += __shfl_xor(ls, 2);
                    ls += __shfl_xor(ls, 4);
                    ls += __shfl_xor(ls, 8);
                    lrow[r] = lrow[r] * alpha + ls;
                    mrow[r] = mnew;
#pragma unroll
                    for (int nt = 0; nt < 8; ++nt) of[nt][r] *= alpha;
                }
                __threadfence_block();

#pragma unroll
                for (int s = 0; s < 2; ++s) {
                    bf16x8 af = *reinterpret_cast<const bf16x8*>(
                        &KPg[(wg * 16 + n16) * 64 + ((s * 32 + quad * 8) ^ xsw)]);
#pragma unroll
                    for (int nt = 0; nt < 8; ++nt) {
                        bf16x8 bf = *reinterpret_cast<const bf16x8*>(
                            &Vtg[(nt * 16 + n16) * 64 + ((s * 32 + quad * 8) ^ xsw)]);
                        of[nt] = __builtin_amdgcn_mfma_f32_16x16x32_bf16(af, bf, of[nt], 0, 0, 0);
                    }
                }
            }
        }

        // ---- merge the two groups' online-softmax partials, group 0 writes out
        __syncthreads();   // all PV reads done; LDS reusable as merge buffer
        if (grp == 1) {
            float* dst = mrg + ((size_t)(wg * 64 + lane)) * 40;
#pragma unroll
            for (int nt = 0; nt < 8; ++nt)
#pragma unroll
                for (int r = 0; r < 4; ++r) dst[nt * 4 + r] = of[nt][r];
#pragma unroll
            for (int r = 0; r < 4; ++r) { dst[32 + r] = mrow[r]; dst[36 + r] = lrow[r]; }
        }
        __syncthreads();
        if (grp == 0) {
            const float* src = mrg + ((size_t)(wg * 64 + lane)) * 40;
#pragma unroll
            for (int r = 0; r < 4; ++r) {
                const float mB = src[32 + r], lB = src[36 + r];
                const float m  = fmaxf(mrow[r], mB);
                const float a  = __expf(mrow[r] - m);
                const float b  = __expf(mB - m);
                const float inv = 1.0f / (lrow[r] * a + lB * b);
                u16* dst = ao + (size_t)(q0 + wg * 16 + quad * 4 + r) * (NH * HD) + h * HD + n16;
#pragma unroll
                for (int nt = 0; nt < 8; ++nt)
                    dst[nt * 16] = f2bf((of[nt][r] * a + src[nt * 4 + r] * b) * inv);
            }
        }
        __syncthreads();   // merge reads done before next half's staging
    }
}

// ---------------------------------------------------------------------------
// Fast-path workspace overlay (bytes), peak 92,274,688:
//   hb     [2048][4096] bf16 @ 0          (16.8M)  A for gemm1; dead after
//   wqkv_b [6144][4096] bf16 @ 16,777,216 (50.3M)  B for gemm1; dead after
//   qb     [32][2048][128]   @ 67,108,864 (16.8M)  written by gemm1 epilogue
//   kb     [ 8][2048][128]   @ 83,886,080 ( 4.2M)
//   vb     [ 8][2048][128]   @ 88,080,384 ( 4.2M)  (ends exactly at 92,274,688)
//   wo_b   [4096][4096] bf16 @ 0          (33.5M)  after gemm1 (hb+wqkv dead)
//   ao     [2048][4096] bf16 @ 33,554,432 (16.8M)
// ---------------------------------------------------------------------------
extern "C" void kernel_launch(void* const* d_in, const int* in_sizes, int n_in,
                              void* d_out, int out_size, void* d_ws, size_t ws_size,
                              hipStream_t stream)
{
    const float* h   = (const float*)d_in[0];
    const int*   pos = (const int*)d_in[1];
    const float* wq  = (const float*)d_in[2];
    const float* wk  = (const float*)d_in[3];
    const float* wv  = (const float*)d_in[4];
    const float* wo  = (const float*)d_in[5];

    char* ws = (char*)d_ws;

    if (ws_size >= 92274688ull) {
        u16* hb     = (u16*)(ws);
        u16* wqkv_b = (u16*)(ws + 16777216);
        u16* qb     = (u16*)(ws + 67108864);
        u16* kb     = (u16*)(ws + 83886080);
        u16* vb     = (u16*)(ws + 88080384);
        u16* wo_b   = (u16*)(ws);
        u16* ao     = (u16*)(ws + 33554432);

        cvt_all<<<16384, 256, 0, stream>>>(h, wq, wk, wv, hb, wqkv_b);
        gemm128<2><<<dim3(NQKV / 128, S_LEN / 128), 256, 0, stream>>>(
            hb, wqkv_b, nullptr, HID, 0, pos, qb, kb, vb);
        cvt_f32_bf16<<<8192, 256, 0, stream>>>(wo, wo_b, 2097152);
        attn_mfma<<<dim3(S_LEN / 128, NH), 512, 0, stream>>>(qb, kb, vb, ao);
        gemm128<0><<<dim3(HID / 128, S_LEN / 128), 256, 0, stream>>>(
            ao, wo_b, d_out, NH * HD, HID, nullptr, nullptr, nullptr, nullptr);
    } else {
        // ---- fallback (R3 layout, 64 MB)
        u16* qkv = (u16*)(ws);
        u16* qb  = (u16*)(ws + 25165824);
        u16* kb  = (u16*)(ws + 41943040);
        u16* vb  = (u16*)(ws + 46137344);
        u16* ao  = (u16*)(ws + 50331648);

        dim3 g1(NQKV / 64, S_LEN / 64);
        gemm_bt<true, true><<<g1, 256, 0, stream>>>(
            h, wq, NH * HD, wk, NH * HD + NKV * HD, wv, qkv, HID, NQKV);
        rope_kernel<<<S_LEN, 256, 0, stream>>>(qkv, pos, qb, kb, vb);
        attn_mfma<<<dim3(S_LEN / 128, NH), 512, 0, stream>>>(qb, kb, vb, ao);
        dim3 g2(HID / 64, S_LEN / 64);
        gemm_bt<false, false><<<g2, 256, 0, stream>>>(
            ao, wo, HID, wo, HID, wo, d_out, NH * HD, HID);
    }
}

// Round 10
// 568.058 us; speedup vs baseline: 3.3876x; 3.3876x over previous
//
#include <hip/hip_runtime.h>
#include <hip/hip_bf16.h>

// Problem constants (Mixtral attention prefill)
#define S_LEN 2048
#define HID 4096
#define NH 32
#define NKV 8
#define HD 128
#define NQKV 6144   // NH*HD + 2*NKV*HD

typedef unsigned short u16;
typedef unsigned int u32;
typedef __bf16 bf16x8 __attribute__((ext_vector_type(8)));
typedef float f32x4 __attribute__((ext_vector_type(4)));

__device__ __forceinline__ float bf2f(u16 u) {
    union { u32 i; float f; } x; x.i = ((u32)u) << 16; return x.f;
}
__device__ __forceinline__ u16 f2bf(float f) {
    union { float f; u32 i; } x; x.f = f;
    u32 r = x.i + 0x7fffu + ((x.i >> 16) & 1u);   // RNE
    return (u16)(r >> 16);
}
__device__ __forceinline__ u32 pack2(float a, float b) {
    return (u32)f2bf(a) | ((u32)f2bf(b) << 16);
}
// async global->LDS, 16 B per lane; LDS dest is wave-uniform base + lane*16
__device__ __forceinline__ void gld16(const u16* g, u16* l) {
    __builtin_amdgcn_global_load_lds(
        (const __attribute__((address_space(1))) u32*)g,
        (__attribute__((address_space(3))) u32*)l, 16, 0, 0);
}

// ---------------------------------------------------------------------------
// fp32 -> bf16 convert (8 elems/thread), n8 = n/8
// ---------------------------------------------------------------------------
__global__ __launch_bounds__(256) void cvt_f32_bf16(
    const float* __restrict__ src, u16* __restrict__ dst, int n8)
{
    int i = blockIdx.x * 256 + threadIdx.x;
    if (i >= n8) return;
    const float4* s = (const float4*)src + (size_t)i * 2;
    float4 x0 = s[0], x1 = s[1];
    uint4 p;
    p.x = pack2(x0.x, x0.y); p.y = pack2(x0.z, x0.w);
    p.z = pack2(x1.x, x1.y); p.w = pack2(x1.z, x1.w);
    *((uint4*)dst + i) = p;
}

// ---------------------------------------------------------------------------
// All four pre-GEMM converts in ONE launch (h, wq, wk, wv).
// i-space: [0,1048576) h | [.,3145728) wq | [.,3670016) wk | [.,4194304) wv
// ---------------------------------------------------------------------------
__global__ __launch_bounds__(256) void cvt_all(
    const float* __restrict__ h, const float* __restrict__ wq,
    const float* __restrict__ wk, const float* __restrict__ wv,
    u16* __restrict__ hb, u16* __restrict__ wqkvb)
{
    int i = blockIdx.x * 256 + threadIdx.x;
    const float* src; u16* dst; int off;
    if (i < 1048576)      { src = h;  dst = hb;               off = i; }
    else if (i < 3145728) { src = wq; dst = wqkvb;            off = i - 1048576; }
    else if (i < 3670016) { src = wk; dst = wqkvb + 16777216; off = i - 3145728; }
    else                  { src = wv; dst = wqkvb + 20971520; off = i - 3670016; }
    const float4* s = (const float4*)src + (size_t)off * 2;
    float4 x0 = s[0], x1 = s[1];
    uint4 p;
    p.x = pack2(x0.x, x0.y); p.y = pack2(x0.z, x0.w);
    p.z = pack2(x1.x, x1.y); p.w = pack2(x1.z, x1.w);
    *((uint4*)dst + off) = p;
}

// ---------------------------------------------------------------------------
// m97-style GEMM (R5-proven form): C[M][N] = X[M][K] * W[N][K]^T, bf16 in,
// fp32 acc. 128x128 tile, BK=32, 4 waves 2x2; 4x4 16x16 C-tiles per wave.
// Staging via global_load_lds width=16. T1 XCD swizzle (grids %8==0).
// NOTE (R6-R9 lesson): do NOT put ocml transcendental CALLS (cosf/sinf) in
// any epilogue of this kernel — a call forces acc out of AGPRs (call-
// clobbered) and the allocator scratch-homes acc -> 5.2 GB spill traffic,
// 10x slowdown. RoPE stays in a separate kernel.
// ---------------------------------------------------------------------------
template <bool OUTBF16>
__global__ __launch_bounds__(256) void gemm128(
    const u16* __restrict__ X, const u16* __restrict__ W,
    void* __restrict__ C, int K, int ldc)
{
    __shared__ __align__(16) u16 As[128 * 32];   // 8 KB
    __shared__ __align__(16) u16 Bs[128 * 32];   // 8 KB

    const int tid  = threadIdx.x;
    const int w    = tid >> 6;
    const int lane = tid & 63;
    const int quad = lane >> 4;
    const int n16  = lane & 15;

    int id = blockIdx.y * gridDim.x + blockIdx.x;
    const int nwg = gridDim.x * gridDim.y;
    if ((nwg & 7) == 0) {
        const int cpx = nwg >> 3;
        id = (id & 7) * cpx + (id >> 3);
    }
    const int m0 = (id / gridDim.x) * 128;
    const int n0 = (id % gridDim.x) * 128;

    const int wr   = (w >> 1) * 64;
    const int wc   = (w & 1) * 64;

    const int c0 = tid;          // staging chunk ids: row=c>>2, koff=(c&3)*8
    const int c1 = tid + 256;

    f32x4 acc[4][4] = {};

    for (int k0 = 0; k0 < K; k0 += 32) {
        __syncthreads();
        // A tile: 128 rows x 32 k (8 KB) in 512 16B chunks
        gld16(X + (size_t)(m0 + (c0 >> 2)) * K + k0 + (c0 & 3) * 8,
              As + (size_t)(w * 64) * 8);
        gld16(X + (size_t)(m0 + (c1 >> 2)) * K + k0 + (c1 & 3) * 8,
              As + (size_t)(256 + w * 64) * 8);
        // B tile
        gld16(W + (size_t)(n0 + (c0 >> 2)) * K + k0 + (c0 & 3) * 8,
              Bs + (size_t)(w * 64) * 8);
        gld16(W + (size_t)(n0 + (c1 >> 2)) * K + k0 + (c1 & 3) * 8,
              Bs + (size_t)(256 + w * 64) * 8);
        __syncthreads();

        bf16x8 a[4], b[4];
#pragma unroll
        for (int t = 0; t < 4; ++t) {
            a[t] = *reinterpret_cast<const bf16x8*>(As + (wr + t * 16 + n16) * 32 + quad * 8);
            b[t] = *reinterpret_cast<const bf16x8*>(Bs + (wc + t * 16 + n16) * 32 + quad * 8);
        }
#pragma unroll
        for (int mt = 0; mt < 4; ++mt)
#pragma unroll
            for (int nt = 0; nt < 4; ++nt)
                acc[mt][nt] = __builtin_amdgcn_mfma_f32_16x16x32_bf16(
                    a[mt], b[nt], acc[mt][nt], 0, 0, 0);
    }

#pragma unroll
    for (int mt = 0; mt < 4; ++mt) {
        const int row0 = m0 + wr + mt * 16 + quad * 4;
#pragma unroll
        for (int nt = 0; nt < 4; ++nt) {
            const int col = n0 + wc + nt * 16 + n16;
#pragma unroll
            for (int r = 0; r < 4; ++r) {
                if constexpr (OUTBF16)
                    ((u16*)C)[(size_t)(row0 + r) * ldc + col] = f2bf(acc[mt][nt][r]);
                else
                    ((float*)C)[(size_t)(row0 + r) * ldc + col] = acc[mt][nt][r];
            }
        }
    }
}

// ---------------------------------------------------------------------------
// Fallback GEMM (R3): fp32 inputs converted on the fly, 64x64 tile.
// ---------------------------------------------------------------------------
template <bool XF32, bool OUTBF16>
__global__ __launch_bounds__(256) void gemm_bt(
    const void* __restrict__ Xv,
    const float* __restrict__ W0, int r1,
    const float* __restrict__ W1, int r2,
    const float* __restrict__ W2,
    void* __restrict__ C, int K, int ldc)
{
    __shared__ u16 Xs[64][48];
    __shared__ u16 Ws[64][48];

    const int tid  = threadIdx.x;
    const int w    = tid >> 6;
    const int lane = tid & 63;
    const int m0   = blockIdx.y * 64;
    const int n0   = blockIdx.x * 64;

    const int sr = tid >> 2;
    const int sc = (tid & 3) * 8;

    const float* xrow32 = nullptr;
    const u16*   xrow16 = nullptr;
    if constexpr (XF32) xrow32 = (const float*)Xv + (size_t)(m0 + sr) * K;
    else                xrow16 = (const u16*)Xv + (size_t)(m0 + sr) * K;

    const int wr = n0 + sr;
    const float* wrow;
    if (wr < r1)      wrow = W0 + (size_t)wr * K;
    else if (wr < r2) wrow = W1 + (size_t)(wr - r1) * K;
    else              wrow = W2 + (size_t)(wr - r2) * K;

    f32x4 acc[4] = {};
    const int mrow = w * 16 + (lane & 15);
    const int nrow = lane & 15;
    const int kq   = (lane >> 4) * 8;

    for (int k0 = 0; k0 < K; k0 += 32) {
        __syncthreads();
        if constexpr (XF32) {
            float4 x0 = *reinterpret_cast<const float4*>(xrow32 + k0 + sc);
            float4 x1 = *reinterpret_cast<const float4*>(xrow32 + k0 + sc + 4);
            uint4 p;
            p.x = pack2(x0.x, x0.y); p.y = pack2(x0.z, x0.w);
            p.z = pack2(x1.x, x1.y); p.w = pack2(x1.z, x1.w);
            *reinterpret_cast<uint4*>(&Xs[sr][sc]) = p;
        } else {
            *reinterpret_cast<uint4*>(&Xs[sr][sc]) =
                *reinterpret_cast<const uint4*>(xrow16 + k0 + sc);
        }
        {
            float4 w0v = *reinterpret_cast<const float4*>(wrow + k0 + sc);
            float4 w1v = *reinterpret_cast<const float4*>(wrow + k0 + sc + 4);
            uint4 p;
            p.x = pack2(w0v.x, w0v.y); p.y = pack2(w0v.z, w0v.w);
            p.z = pack2(w1v.x, w1v.y); p.w = pack2(w1v.z, w1v.w);
            *reinterpret_cast<uint4*>(&Ws[sr][sc]) = p;
        }
        __syncthreads();
        bf16x8 a = *reinterpret_cast<const bf16x8*>(&Xs[mrow][kq]);
#pragma unroll
        for (int t = 0; t < 4; ++t) {
            bf16x8 b = *reinterpret_cast<const bf16x8*>(&Ws[t * 16 + nrow][kq]);
            acc[t] = __builtin_amdgcn_mfma_f32_16x16x32_bf16(a, b, acc[t], 0, 0, 0);
        }
    }

    const int mb = m0 + w * 16 + ((lane >> 4) << 2);
#pragma unroll
    for (int t = 0; t < 4; ++t) {
        const int col = n0 + t * 16 + (lane & 15);
#pragma unroll
        for (int i = 0; i < 4; ++i) {
            if constexpr (OUTBF16)
                ((u16*)C)[(size_t)(mb + i) * ldc + col] = f2bf(acc[t][i]);
            else
                ((float*)C)[(size_t)(mb + i) * ldc + col] = acc[t][i];
        }
    }
}

// ---------------------------------------------------------------------------
// RoPE (half-split, theta=1e6); Q pre-scaled by 1/sqrt(HD).
// ---------------------------------------------------------------------------
__global__ __launch_bounds__(256) void rope_kernel(
    const u16* __restrict__ qkv, const int* __restrict__ pos,
    u16* __restrict__ qb, u16* __restrict__ kb, u16* __restrict__ vb)
{
    const int n   = blockIdx.x;
    const int tid = threadIdx.x;
    const float scale = 0.08838834764831845f;
    __shared__ float cs[64], sn[64];
    if (tid < 64) {
        float p   = (float)pos[n];
        float inv = powf(1.0e6f, -(float)tid / 64.0f);
        float f   = p * inv;
        cs[tid] = cosf(f);
        sn[tid] = sinf(f);
    }
    __syncthreads();
    const u16* row = qkv + (size_t)n * NQKV;

    for (int i = tid; i < NH * 64; i += 256) {
        int h = i >> 6, j = i & 63;
        float x1 = bf2f(row[h * HD + j]), x2 = bf2f(row[h * HD + j + 64]);
        size_t base = ((size_t)h * S_LEN + n) * HD;
        qb[base + j]      = f2bf((x1 * cs[j] - x2 * sn[j]) * scale);
        qb[base + j + 64] = f2bf((x2 * cs[j] + x1 * sn[j]) * scale);
    }
    for (int i = tid; i < NKV * 64; i += 256) {
        int g = i >> 6, j = i & 63;
        const u16* kr = row + NH * HD + g * HD;
        float x1 = bf2f(kr[j]), x2 = bf2f(kr[j + 64]);
        size_t base = ((size_t)g * S_LEN + n) * HD;
        kb[base + j]      = f2bf(x1 * cs[j] - x2 * sn[j]);
        kb[base + j + 64] = f2bf(x2 * cs[j] + x1 * sn[j]);
    }
    for (int i = tid; i < NKV * HD; i += 256) {
        int g = i >> 7, d = i & 127;
        vb[((size_t)g * S_LEN + n) * HD + d] = row[NH * HD + NKV * HD + g * HD + d];
    }
}

// ---------------------------------------------------------------------------
// MFMA flash attention (causal GQA).
// R5: q-tile pairing (i, 31-i); R6: XOR-swizzled LDS, P aliases K buffer;
// R7: in-block split-K (8 waves, even/odd K-tiles); R8/R9: bounds (512,2),
// K via global_load_lds with pre-swizzled source (T21).
// ---------------------------------------------------------------------------
__global__ __launch_bounds__(512, 2) void attn_mfma(
    const u16* __restrict__ qb, const u16* __restrict__ kb,
    const u16* __restrict__ vb, u16* __restrict__ ao)
{
    // 64 KB: KP[2] (16 KB each; softmax P aliases low 8 KB), Vt[2] (16 KB each)
    __shared__ __align__(16) u16 smem[32768];

    const int tid  = threadIdx.x;
    const int gtid = tid & 255;        // id within group
    const int grp  = tid >> 8;         // 0: even tiles, 1: odd tiles
    const int wg   = (tid >> 6) & 3;   // wave within group
    const int lane = tid & 63;
    const int quad = lane >> 4;
    const int n16  = lane & 15;
    const int h    = blockIdx.y;
    const int g    = h >> 2;
    const int NQT  = S_LEN / 64;       // 32 q-tiles

    u16* KPg = smem + grp * 8192;            // 64 x 128 (stride 128)
    u16* Vtg = smem + 16384 + grp * 8192;    // 128 x 64 (stride 64)
    float* mrg = reinterpret_cast<float*>(smem);  // merge buffer (40 KB)

    const u16* kbase = kb + (size_t)g * S_LEN * HD;
    const u16* vbase = vb + (size_t)g * S_LEN * HD;
    const int xsw = (n16 & 7) << 3;   // read-side XOR swizzle (u16 units)

    // K staging: call i, chunk c = i*256 + gtid ->
    //   LDS row = i*16 + (gtid>>4), col = (gtid&15)*8 (linear dest);
    //   source col pre-swizzled so LDS[row][c] = K[row][c ^ ((row&7)<<3)].
    const int krow = gtid >> 4;                                // 0..15
    const int kcol = ((gtid & 15) ^ ((gtid >> 4) & 7)) << 3;   // pre-swizzled
    u16* kdst = KPg + (size_t)(wg * 64) * 8;                   // + i*256*8

    for (int half = 0; half < 2; ++half) {
        const int qt = half ? (NQT - 1 - blockIdx.x) : blockIdx.x;
        const int q0 = qt * 64;

        bf16x8 qf[4];
        {
            const u16* qrow = qb + ((size_t)h * S_LEN + q0 + wg * 16 + n16) * HD;
#pragma unroll
            for (int s = 0; s < 4; ++s)
                qf[s] = *reinterpret_cast<const bf16x8*>(qrow + s * 32 + quad * 8);
        }

        f32x4 of[8] = {};
        float mrow[4], lrow[4];
#pragma unroll
        for (int r = 0; r < 4; ++r) { mrow[r] = -1e30f; lrow[r] = 0.0f; }

        uint4 vreg[4];
        auto load_v = [&](int k0) {
#pragma unroll
            for (int i = 0; i < 4; ++i)
                vreg[i] = *reinterpret_cast<const uint4*>(
                    vbase + (size_t)(k0 + lane) * HD + wg * 8 + i * 32);
        };
        load_v(grp * 64);   // prologue: this group's first tile

        const int ntiles = qt + 1;
        const int nIt = (ntiles + 1) >> 1;
        for (int it = 0; it < nIt; ++it) {
            const int kt = 2 * it + grp;
            const bool act = (kt < ntiles);

            __syncthreads();   // prev tile's PV / merge reads done; LDS free
            if (act) {
                const int k0 = kt * 64;
#pragma unroll
                for (int i = 0; i < 4; ++i)
                    gld16(kbase + (size_t)(k0 + i * 16 + krow) * HD + kcol,
                          kdst + (size_t)(i * 256) * 8);
#pragma unroll
                for (int i = 0; i < 4; ++i) {
                    const int d0 = wg * 8 + i * 32;
                    const u32 vw[4] = {vreg[i].x, vreg[i].y, vreg[i].z, vreg[i].w};
#pragma unroll
                    for (int t = 0; t < 4; ++t) {
                        const int r0 = d0 + 2 * t;
                        Vtg[r0 * 64 + (lane ^ ((r0 & 7) << 3))]             = (u16)(vw[t] & 0xffff);
                        Vtg[(r0 + 1) * 64 + (lane ^ (((r0 + 1) & 7) << 3))] = (u16)(vw[t] >> 16);
                    }
                }
            }
            __syncthreads();   // staging visible
            if (kt + 2 < ntiles) load_v((kt + 2) * 64);

            f32x4 sc[4] = {};
            if (act) {
#pragma unroll
                for (int s = 0; s < 4; ++s) {
#pragma unroll
                    for (int t = 0; t < 4; ++t) {
                        bf16x8 bf = *reinterpret_cast<const bf16x8*>(
                            &KPg[(t * 16 + n16) * 128 + ((s * 32 + quad * 8) ^ xsw)]);
                        sc[t] = __builtin_amdgcn_mfma_f32_16x16x32_bf16(qf[s], bf, sc[t], 0, 0, 0);
                    }
                }
                if (kt == qt) {   // diagonal tile: causal mask
                    const int qbase = q0 + wg * 16 + quad * 4;
#pragma unroll
                    for (int t = 0; t < 4; ++t) {
                        int key = kt * 64 + t * 16 + n16;
#pragma unroll
                        for (int r = 0; r < 4; ++r)
                            if (key > qbase + r) sc[t][r] = -1e30f;
                    }
                }
            }

            __syncthreads();   // group's waves done reading K; P may overwrite

            if (act) {
#pragma unroll
                for (int r = 0; r < 4; ++r) {
                    float mx = fmaxf(fmaxf(sc[0][r], sc[1][r]), fmaxf(sc[2][r], sc[3][r]));
                    mx = fmaxf(mx, __shfl_xor(mx, 1));
                    mx = fmaxf(mx, __shfl_xor(mx, 2));
                    mx = fmaxf(mx, __shfl_xor(mx, 4));
                    mx = fmaxf(mx, __shfl_xor(mx, 8));
                    float mnew  = fmaxf(mrow[r], mx);
                    float alpha = __expf(mrow[r] - mnew);
                    float ls = 0.0f;
                    const int pr = quad * 4 + r;
#pragma unroll
                    for (int t = 0; t < 4; ++t) {
                        float p = __expf(sc[t][r] - mnew);
                        KPg[(wg * 16 + pr) * 64 + ((t * 16 + n16) ^ ((pr & 7) << 3))] = f2bf(p);
                        ls += p;
                    }
                    ls += __shfl_xor(ls, 1);
                    ls += __shfl_xor(ls, 2);
                    ls += __shfl_xor(ls, 4);
                    ls += __shfl_xor(ls, 8);
                    lrow[r] = lrow[r] * alpha + ls;
                    mrow[r] = mnew;
#pragma unroll
                    for (int nt = 0; nt < 8; ++nt) of[nt][r] *= alpha;
                }
                __threadfence_block();

#pragma unroll
                for (int s = 0; s < 2; ++s) {
                    bf16x8 af = *reinterpret_cast<const bf16x8*>(
                        &KPg[(wg * 16 + n16) * 64 + ((s * 32 + quad * 8) ^ xsw)]);
#pragma unroll
                    for (int nt = 0; nt < 8; ++nt) {
                        bf16x8 bf = *reinterpret_cast<const bf16x8*>(
                            &Vtg[(nt * 16 + n16) * 64 + ((s * 32 + quad * 8) ^ xsw)]);
                        of[nt] = __builtin_amdgcn_mfma_f32_16x16x32_bf16(af, bf, of[nt], 0, 0, 0);
                    }
                }
            }
        }

        // ---- merge the two groups' online-softmax partials, group 0 writes out
        __syncthreads();   // all PV reads done; LDS reusable as merge buffer
        if (grp == 1) {
            float* dst = mrg + ((size_t)(wg * 64 + lane)) * 40;
#pragma unroll
            for (int nt = 0; nt < 8; ++nt)
#pragma unroll
                for (int r = 0; r < 4; ++r) dst[nt * 4 + r] = of[nt][r];
#pragma unroll
            for (int r = 0; r < 4; ++r) { dst[32 + r] = mrow[r]; dst[36 + r] = lrow[r]; }
        }
        __syncthreads();
        if (grp == 0) {
            const float* src = mrg + ((size_t)(wg * 64 + lane)) * 40;
#pragma unroll
            for (int r = 0; r < 4; ++r) {
                const float mB = src[32 + r], lB = src[36 + r];
                const float m  = fmaxf(mrow[r], mB);
                const float a  = __expf(mrow[r] - m);
                const float b  = __expf(mB - m);
                const float inv = 1.0f / (lrow[r] * a + lB * b);
                u16* dst = ao + (size_t)(q0 + wg * 16 + quad * 4 + r) * (NH * HD) + h * HD + n16;
#pragma unroll
                for (int nt = 0; nt < 8; ++nt)
                    dst[nt * 16] = f2bf((of[nt][r] * a + src[nt * 4 + r] * b) * inv);
            }
        }
        __syncthreads();   // merge reads done before next half's staging
    }
}

// ---------------------------------------------------------------------------
// Fast-path workspace overlay (bytes), peak 92,274,688 (R5-proven layout):
//   hb   [2048][4096] bf16 @ 0           (16.8M)  -> reused as qb after gemm1
//   wqkv [6144][4096] bf16 @ 16,777,216  (50.3M)  -> dead after gemm1:
//        ao @ 16,777,216 (16.8M) | kb @ 33,554,432 | vb @ 37,748,736
//   wo_b [4096][4096] bf16 @ 41,943,040  (33.5M)  (converted after rope;
//        overlays wqkv tail + qkv head, both dead by then)
//   qkv  [2048][6144] bf16 @ 67,108,864  (25.2M)  -> dead after rope
// ---------------------------------------------------------------------------
extern "C" void kernel_launch(void* const* d_in, const int* in_sizes, int n_in,
                              void* d_out, int out_size, void* d_ws, size_t ws_size,
                              hipStream_t stream)
{
    const float* h   = (const float*)d_in[0];
    const int*   pos = (const int*)d_in[1];
    const float* wq  = (const float*)d_in[2];
    const float* wk  = (const float*)d_in[3];
    const float* wv  = (const float*)d_in[4];
    const float* wo  = (const float*)d_in[5];

    char* ws = (char*)d_ws;

    if (ws_size >= 92274688ull) {
        u16* hb     = (u16*)(ws);
        u16* wqkv_b = (u16*)(ws + 16777216);
        u16* ao     = (u16*)(ws + 16777216);
        u16* kb     = (u16*)(ws + 33554432);
        u16* vb     = (u16*)(ws + 37748736);
        u16* wo_b   = (u16*)(ws + 41943040);
        u16* qkv    = (u16*)(ws + 67108864);
        u16* qb     = hb;

        cvt_all<<<16384, 256, 0, stream>>>(h, wq, wk, wv, hb, wqkv_b);
        gemm128<true><<<dim3(NQKV / 128, S_LEN / 128), 256, 0, stream>>>(
            hb, wqkv_b, qkv, HID, NQKV);
        rope_kernel<<<S_LEN, 256, 0, stream>>>(qkv, pos, qb, kb, vb);
        cvt_f32_bf16<<<8192, 256, 0, stream>>>(wo, wo_b, 2097152);
        attn_mfma<<<dim3(S_LEN / 128, NH), 512, 0, stream>>>(qb, kb, vb, ao);
        gemm128<false><<<dim3(HID / 128, S_LEN / 128), 256, 0, stream>>>(
            ao, wo_b, d_out, NH * HD, HID);
    } else {
        // ---- fallback (R3 layout, 64 MB)
        u16* qkv = (u16*)(ws);
        u16* qb  = (u16*)(ws + 25165824);
        u16* kb  = (u16*)(ws + 41943040);
        u16* vb  = (u16*)(ws + 46137344);
        u16* ao  = (u16*)(ws + 50331648);

        dim3 g1(NQKV / 64, S_LEN / 64);
        gemm_bt<true, true><<<g1, 256, 0, stream>>>(
            h, wq, NH * HD, wk, NH * HD + NKV * HD, wv, qkv, HID, NQKV);
        rope_kernel<<<S_LEN, 256, 0, stream>>>(qkv, pos, qb, kb, vb);
        attn_mfma<<<dim3(S_LEN / 128, NH), 512, 0, stream>>>(qb, kb, vb, ao);
        dim3 g2(HID / 64, S_LEN / 64);
        gemm_bt<false, false><<<g2, 256, 0, stream>>>(
            ao, wo, HID, wo, HID, wo, d_out, NH * HD, HID);
    }
}

// Round 11
// 558.072 us; speedup vs baseline: 3.4482x; 1.0179x over previous
//
#include <hip/hip_runtime.h>
#include <hip/hip_bf16.h>

// Problem constants (Mixtral attention prefill)
#define S_LEN 2048
#define HID 4096
#define NH 32
#define NKV 8
#define HD 128
#define NQKV 6144   // NH*HD + 2*NKV*HD

typedef unsigned short u16;
typedef unsigned int u32;
typedef __bf16 bf16x8 __attribute__((ext_vector_type(8)));
typedef float f32x4 __attribute__((ext_vector_type(4)));

__device__ __forceinline__ float bf2f(u16 u) {
    union { u32 i; float f; } x; x.i = ((u32)u) << 16; return x.f;
}
__device__ __forceinline__ u16 f2bf(float f) {
    union { float f; u32 i; } x; x.f = f;
    u32 r = x.i + 0x7fffu + ((x.i >> 16) & 1u);   // RNE
    return (u16)(r >> 16);
}
__device__ __forceinline__ u32 pack2(float a, float b) {
    return (u32)f2bf(a) | ((u32)f2bf(b) << 16);
}
// async global->LDS, 16 B per lane; LDS dest is wave-uniform base + lane*16
__device__ __forceinline__ void gld16(const u16* g, u16* l) {
    __builtin_amdgcn_global_load_lds(
        (const __attribute__((address_space(1))) u32*)g,
        (__attribute__((address_space(3))) u32*)l, 16, 0, 0);
}

// ---------------------------------------------------------------------------
// fp32 -> bf16 convert (8 elems/thread), n8 = n/8
// ---------------------------------------------------------------------------
__global__ __launch_bounds__(256) void cvt_f32_bf16(
    const float* __restrict__ src, u16* __restrict__ dst, int n8)
{
    int i = blockIdx.x * 256 + threadIdx.x;
    if (i >= n8) return;
    const float4* s = (const float4*)src + (size_t)i * 2;
    float4 x0 = s[0], x1 = s[1];
    uint4 p;
    p.x = pack2(x0.x, x0.y); p.y = pack2(x0.z, x0.w);
    p.z = pack2(x1.x, x1.y); p.w = pack2(x1.z, x1.w);
    *((uint4*)dst + i) = p;
}

// ---------------------------------------------------------------------------
// All four pre-GEMM converts in ONE launch (h, wq, wk, wv).
// i-space: [0,1048576) h | [.,3145728) wq | [.,3670016) wk | [.,4194304) wv
// ---------------------------------------------------------------------------
__global__ __launch_bounds__(256) void cvt_all(
    const float* __restrict__ h, const float* __restrict__ wq,
    const float* __restrict__ wk, const float* __restrict__ wv,
    u16* __restrict__ hb, u16* __restrict__ wqkvb)
{
    int i = blockIdx.x * 256 + threadIdx.x;
    const float* src; u16* dst; int off;
    if (i < 1048576)      { src = h;  dst = hb;               off = i; }
    else if (i < 3145728) { src = wq; dst = wqkvb;            off = i - 1048576; }
    else if (i < 3670016) { src = wk; dst = wqkvb + 16777216; off = i - 3145728; }
    else                  { src = wv; dst = wqkvb + 20971520; off = i - 3670016; }
    const float4* s = (const float4*)src + (size_t)off * 2;
    float4 x0 = s[0], x1 = s[1];
    uint4 p;
    p.x = pack2(x0.x, x0.y); p.y = pack2(x0.z, x0.w);
    p.z = pack2(x1.x, x1.y); p.w = pack2(x1.z, x1.w);
    *((uint4*)dst + off) = p;
}

// ---------------------------------------------------------------------------
// R11: cos/sin table for fused RoPE. tab[row*64+j] = cos(pos[row]*inv(j)),
// tab[131072 + row*64+j] = sin(...). 131072 entries, grid 512.
// Transcendental CALLS are confined to THIS kernel (R6-R9 lesson: a call in
// the GEMM forces acc out of AGPRs -> 5.2 GB scratch spill).
// ---------------------------------------------------------------------------
__global__ __launch_bounds__(256) void rope_table(
    const int* __restrict__ pos, float* __restrict__ tab)
{
    int idx = blockIdx.x * 256 + threadIdx.x;   // < 131072
    int row = idx >> 6, j = idx & 63;
    float p   = (float)pos[row];
    float inv = exp2f(-0.31143075889569023f * (float)j);  // 1e6^(-j/64)
    float f   = p * inv;
    tab[idx]          = cosf(f);
    tab[idx + 131072] = sinf(f);
}

// ---------------------------------------------------------------------------
// m97-style GEMM: C[M][N] = X[M][K] * W[N][K]^T, bf16 in, fp32 acc.
// 128x128 tile, BK=32, 4 waves 2x2; 4x4 16x16 C-tiles per wave.
// Staging via global_load_lds width=16. T1 XCD swizzle (grids %8==0).
// EPI: 0 = f32 C, 1 = bf16 C, 2 = fused RoPE -> qb/kb/vb (head-major).
// EPI==2: B-columns remapped to {(w&1)*32 + {0,16,64,80}} so one thread
// holds the RoPE pair (j, j+64) in acc[mt][t]/acc[mt][t+2]; cos/sin come
// from the precomputed table (NO transcendental calls -> acc stays in
// AGPRs; R6-R9's 10x spill regression was ocml cosf/sinf calls).
// ---------------------------------------------------------------------------
template <int EPI>
__global__ __launch_bounds__(256) void gemm128(
    const u16* __restrict__ X, const u16* __restrict__ W,
    void* __restrict__ C, int K, int ldc,
    const float* __restrict__ tab,
    u16* __restrict__ qbO, u16* __restrict__ kbO, u16* __restrict__ vbO)
{
    __shared__ __align__(16) u16 As[128 * 32];   // 8 KB
    __shared__ __align__(16) u16 Bs[128 * 32];   // 8 KB

    const int tid  = threadIdx.x;
    const int w    = tid >> 6;
    const int lane = tid & 63;
    const int quad = lane >> 4;
    const int n16  = lane & 15;

    int id = blockIdx.y * gridDim.x + blockIdx.x;
    const int nwg = gridDim.x * gridDim.y;
    if ((nwg & 7) == 0) {
        const int cpx = nwg >> 3;
        id = (id & 7) * cpx + (id >> 3);
    }
    const int m0 = (id / gridDim.x) * 128;
    const int n0 = (id % gridDim.x) * 128;

    const int wr = (w >> 1) * 64;
    const int wc = (w & 1) * 64;

    const int c0 = tid;          // staging chunk ids: row=c>>2, koff=(c&3)*8
    const int c1 = tid + 256;

    f32x4 acc[4][4] = {};

    for (int k0 = 0; k0 < K; k0 += 32) {
        __syncthreads();
        gld16(X + (size_t)(m0 + (c0 >> 2)) * K + k0 + (c0 & 3) * 8,
              As + (size_t)(w * 64) * 8);
        gld16(X + (size_t)(m0 + (c1 >> 2)) * K + k0 + (c1 & 3) * 8,
              As + (size_t)(256 + w * 64) * 8);
        gld16(W + (size_t)(n0 + (c0 >> 2)) * K + k0 + (c0 & 3) * 8,
              Bs + (size_t)(w * 64) * 8);
        gld16(W + (size_t)(n0 + (c1 >> 2)) * K + k0 + (c1 & 3) * 8,
              Bs + (size_t)(256 + w * 64) * 8);
        __syncthreads();

        bf16x8 a[4], b[4];
#pragma unroll
        for (int t = 0; t < 4; ++t) {
            const int bc = (EPI == 2)
                ? ((w & 1) * 32 + (t & 1) * 16 + (t >> 1) * 64)
                : (wc + t * 16);
            a[t] = *reinterpret_cast<const bf16x8*>(As + (wr + t * 16 + n16) * 32 + quad * 8);
            b[t] = *reinterpret_cast<const bf16x8*>(Bs + (bc + n16) * 32 + quad * 8);
        }
#pragma unroll
        for (int mt = 0; mt < 4; ++mt)
#pragma unroll
            for (int nt = 0; nt < 4; ++nt)
                acc[mt][nt] = __builtin_amdgcn_mfma_f32_16x16x32_bf16(
                    a[mt], b[nt], acc[mt][nt], 0, 0, 0);
    }

    if constexpr (EPI == 2) {
        const int ht = n0 >> 7;               // head tile 0..47
        if (ht >= 40) {                       // ---- v: plain head-major store
            const int gg = ht - 40;
#pragma unroll
            for (int mt = 0; mt < 4; ++mt)
#pragma unroll
                for (int nt = 0; nt < 4; ++nt) {
                    const int col = (w & 1) * 32 + (nt & 1) * 16 + (nt >> 1) * 64 + n16;
#pragma unroll
                    for (int r = 0; r < 4; ++r) {
                        const int row = wr + mt * 16 + quad * 4 + r;
                        vbO[((size_t)gg * S_LEN + m0 + row) * HD + col] =
                            f2bf(acc[mt][nt][r]);
                    }
                }
            return;
        }
        // ---- q/k: RoPE with table cos/sin (call-free; acc stays in AGPRs)
        u16* out = (ht < 32) ? qbO : kbO;
        const int hh = (ht < 32) ? ht : ht - 32;
        const float qs = (ht < 32) ? 0.08838834764831845f : 1.0f;
#pragma unroll
        for (int mt = 0; mt < 4; ++mt)
#pragma unroll
            for (int r = 0; r < 4; ++r) {
                const int row = wr + mt * 16 + quad * 4 + r;
                const size_t base = ((size_t)hh * S_LEN + m0 + row) * HD;
                const int trow = (m0 + row) << 6;
#pragma unroll
                for (int t = 0; t < 2; ++t) {
                    const int j = (w & 1) * 32 + t * 16 + n16;
                    const float cv = tab[trow + j];
                    const float sv = tab[131072 + trow + j];
                    const float x1 = acc[mt][t][r], x2 = acc[mt][t + 2][r];
                    out[base + j]      = f2bf((x1 * cv - x2 * sv) * qs);
                    out[base + j + 64] = f2bf((x2 * cv + x1 * sv) * qs);
                }
            }
        return;
    }

#pragma unroll
    for (int mt = 0; mt < 4; ++mt) {
        const int row0 = m0 + wr + mt * 16 + quad * 4;
#pragma unroll
        for (int nt = 0; nt < 4; ++nt) {
            const int col = n0 + wc + nt * 16 + n16;
#pragma unroll
            for (int r = 0; r < 4; ++r) {
                if constexpr (EPI == 1)
                    ((u16*)C)[(size_t)(row0 + r) * ldc + col] = f2bf(acc[mt][nt][r]);
                else
                    ((float*)C)[(size_t)(row0 + r) * ldc + col] = acc[mt][nt][r];
            }
        }
    }
}

// ---------------------------------------------------------------------------
// Fallback GEMM (R3): fp32 inputs converted on the fly, 64x64 tile.
// ---------------------------------------------------------------------------
template <bool XF32, bool OUTBF16>
__global__ __launch_bounds__(256) void gemm_bt(
    const void* __restrict__ Xv,
    const float* __restrict__ W0, int r1,
    const float* __restrict__ W1, int r2,
    const float* __restrict__ W2,
    void* __restrict__ C, int K, int ldc)
{
    __shared__ u16 Xs[64][48];
    __shared__ u16 Ws[64][48];

    const int tid  = threadIdx.x;
    const int w    = tid >> 6;
    const int lane = tid & 63;
    const int m0   = blockIdx.y * 64;
    const int n0   = blockIdx.x * 64;

    const int sr = tid >> 2;
    const int sc = (tid & 3) * 8;

    const float* xrow32 = nullptr;
    const u16*   xrow16 = nullptr;
    if constexpr (XF32) xrow32 = (const float*)Xv + (size_t)(m0 + sr) * K;
    else                xrow16 = (const u16*)Xv + (size_t)(m0 + sr) * K;

    const int wr = n0 + sr;
    const float* wrow;
    if (wr < r1)      wrow = W0 + (size_t)wr * K;
    else if (wr < r2) wrow = W1 + (size_t)(wr - r1) * K;
    else              wrow = W2 + (size_t)(wr - r2) * K;

    f32x4 acc[4] = {};
    const int mrow = w * 16 + (lane & 15);
    const int nrow = lane & 15;
    const int kq   = (lane >> 4) * 8;

    for (int k0 = 0; k0 < K; k0 += 32) {
        __syncthreads();
        if constexpr (XF32) {
            float4 x0 = *reinterpret_cast<const float4*>(xrow32 + k0 + sc);
            float4 x1 = *reinterpret_cast<const float4*>(xrow32 + k0 + sc + 4);
            uint4 p;
            p.x = pack2(x0.x, x0.y); p.y = pack2(x0.z, x0.w);
            p.z = pack2(x1.x, x1.y); p.w = pack2(x1.z, x1.w);
            *reinterpret_cast<uint4*>(&Xs[sr][sc]) = p;
        } else {
            *reinterpret_cast<uint4*>(&Xs[sr][sc]) =
                *reinterpret_cast<const uint4*>(xrow16 + k0 + sc);
        }
        {
            float4 w0v = *reinterpret_cast<const float4*>(wrow + k0 + sc);
            float4 w1v = *reinterpret_cast<const float4*>(wrow + k0 + sc + 4);
            uint4 p;
            p.x = pack2(w0v.x, w0v.y); p.y = pack2(w0v.z, w0v.w);
            p.z = pack2(w1v.x, w1v.y); p.w = pack2(w1v.z, w1v.w);
            *reinterpret_cast<uint4*>(&Ws[sr][sc]) = p;
        }
        __syncthreads();
        bf16x8 a = *reinterpret_cast<const bf16x8*>(&Xs[mrow][kq]);
#pragma unroll
        for (int t = 0; t < 4; ++t) {
            bf16x8 b = *reinterpret_cast<const bf16x8*>(&Ws[t * 16 + nrow][kq]);
            acc[t] = __builtin_amdgcn_mfma_f32_16x16x32_bf16(a, b, acc[t], 0, 0, 0);
        }
    }

    const int mb = m0 + w * 16 + ((lane >> 4) << 2);
#pragma unroll
    for (int t = 0; t < 4; ++t) {
        const int col = n0 + t * 16 + (lane & 15);
#pragma unroll
        for (int i = 0; i < 4; ++i) {
            if constexpr (OUTBF16)
                ((u16*)C)[(size_t)(mb + i) * ldc + col] = f2bf(acc[t][i]);
            else
                ((float*)C)[(size_t)(mb + i) * ldc + col] = acc[t][i];
        }
    }
}

// ---------------------------------------------------------------------------
// RoPE (half-split, theta=1e6); Q pre-scaled by 1/sqrt(HD).  (fallback only)
// ---------------------------------------------------------------------------
__global__ __launch_bounds__(256) void rope_kernel(
    const u16* __restrict__ qkv, const int* __restrict__ pos,
    u16* __restrict__ qb, u16* __restrict__ kb, u16* __restrict__ vb)
{
    const int n   = blockIdx.x;
    const int tid = threadIdx.x;
    const float scale = 0.08838834764831845f;
    __shared__ float cs[64], sn[64];
    if (tid < 64) {
        float p   = (float)pos[n];
        float inv = powf(1.0e6f, -(float)tid / 64.0f);
        float f   = p * inv;
        cs[tid] = cosf(f);
        sn[tid] = sinf(f);
    }
    __syncthreads();
    const u16* row = qkv + (size_t)n * NQKV;

    for (int i = tid; i < NH * 64; i += 256) {
        int h = i >> 6, j = i & 63;
        float x1 = bf2f(row[h * HD + j]), x2 = bf2f(row[h * HD + j + 64]);
        size_t base = ((size_t)h * S_LEN + n) * HD;
        qb[base + j]      = f2bf((x1 * cs[j] - x2 * sn[j]) * scale);
        qb[base + j + 64] = f2bf((x2 * cs[j] + x1 * sn[j]) * scale);
    }
    for (int i = tid; i < NKV * 64; i += 256) {
        int g = i >> 6, j = i & 63;
        const u16* kr = row + NH * HD + g * HD;
        float x1 = bf2f(kr[j]), x2 = bf2f(kr[j + 64]);
        size_t base = ((size_t)g * S_LEN + n) * HD;
        kb[base + j]      = f2bf(x1 * cs[j] - x2 * sn[j]);
        kb[base + j + 64] = f2bf(x2 * cs[j] + x1 * sn[j]);
    }
    for (int i = tid; i < NKV * HD; i += 256) {
        int g = i >> 7, d = i & 127;
        vb[((size_t)g * S_LEN + n) * HD + d] = row[NH * HD + NKV * HD + g * HD + d];
    }
}

// ---------------------------------------------------------------------------
// MFMA flash attention (causal GQA).
// R5: q-tile pairing (i, 31-i); R6: XOR-swizzled LDS, P aliases K buffer;
// R7: in-block split-K (8 waves, even/odd K-tiles); R8/R9: bounds (512,2),
// K via global_load_lds with pre-swizzled source (T21).
// ---------------------------------------------------------------------------
__global__ __launch_bounds__(512, 2) void attn_mfma(
    const u16* __restrict__ qb, const u16* __restrict__ kb,
    const u16* __restrict__ vb, u16* __restrict__ ao)
{
    // 64 KB: KP[2] (16 KB each; softmax P aliases low 8 KB), Vt[2] (16 KB each)
    __shared__ __align__(16) u16 smem[32768];

    const int tid  = threadIdx.x;
    const int gtid = tid & 255;        // id within group
    const int grp  = tid >> 8;         // 0: even tiles, 1: odd tiles
    const int wg   = (tid >> 6) & 3;   // wave within group
    const int lane = tid & 63;
    const int quad = lane >> 4;
    const int n16  = lane & 15;
    const int h    = blockIdx.y;
    const int g    = h >> 2;
    const int NQT  = S_LEN / 64;       // 32 q-tiles

    u16* KPg = smem + grp * 8192;            // 64 x 128 (stride 128)
    u16* Vtg = smem + 16384 + grp * 8192;    // 128 x 64 (stride 64)
    float* mrg = reinterpret_cast<float*>(smem);  // merge buffer (40 KB)

    const u16* kbase = kb + (size_t)g * S_LEN * HD;
    const u16* vbase = vb + (size_t)g * S_LEN * HD;
    const int xsw = (n16 & 7) << 3;   // read-side XOR swizzle (u16 units)

    // K staging: call i, chunk c = i*256 + gtid ->
    //   LDS row = i*16 + (gtid>>4), col = (gtid&15)*8 (linear dest);
    //   source col pre-swizzled so LDS[row][c] = K[row][c ^ ((row&7)<<3)].
    const int krow = gtid >> 4;                                // 0..15
    const int kcol = ((gtid & 15) ^ ((gtid >> 4) & 7)) << 3;   // pre-swizzled
    u16* kdst = KPg + (size_t)(wg * 64) * 8;                   // + i*256*8

    for (int half = 0; half < 2; ++half) {
        const int qt = half ? (NQT - 1 - blockIdx.x) : blockIdx.x;
        const int q0 = qt * 64;

        bf16x8 qf[4];
        {
            const u16* qrow = qb + ((size_t)h * S_LEN + q0 + wg * 16 + n16) * HD;
#pragma unroll
            for (int s = 0; s < 4; ++s)
                qf[s] = *reinterpret_cast<const bf16x8*>(qrow + s * 32 + quad * 8);
        }

        f32x4 of[8] = {};
        float mrow[4], lrow[4];
#pragma unroll
        for (int r = 0; r < 4; ++r) { mrow[r] = -1e30f; lrow[r] = 0.0f; }

        uint4 vreg[4];
        auto load_v = [&](int k0) {
#pragma unroll
            for (int i = 0; i < 4; ++i)
                vreg[i] = *reinterpret_cast<const uint4*>(
                    vbase + (size_t)(k0 + lane) * HD + wg * 8 + i * 32);
        };
        load_v(grp * 64);   // prologue: this group's first tile

        const int ntiles = qt + 1;
        const int nIt = (ntiles + 1) >> 1;
        for (int it = 0; it < nIt; ++it) {
            const int kt = 2 * it + grp;
            const bool act = (kt < ntiles);

            __syncthreads();   // prev tile's PV / merge reads done; LDS free
            if (act) {
                const int k0 = kt * 64;
#pragma unroll
                for (int i = 0; i < 4; ++i)
                    gld16(kbase + (size_t)(k0 + i * 16 + krow) * HD + kcol,
                          kdst + (size_t)(i * 256) * 8);
#pragma unroll
                for (int i = 0; i < 4; ++i) {
                    const int d0 = wg * 8 + i * 32;
                    const u32 vw[4] = {vreg[i].x, vreg[i].y, vreg[i].z, vreg[i].w};
#pragma unroll
                    for (int t = 0; t < 4; ++t) {
                        const int r0 = d0 + 2 * t;
                        Vtg[r0 * 64 + (lane ^ ((r0 & 7) << 3))]             = (u16)(vw[t] & 0xffff);
                        Vtg[(r0 + 1) * 64 + (lane ^ (((r0 + 1) & 7) << 3))] = (u16)(vw[t] >> 16);
                    }
                }
            }
            __syncthreads();   // staging visible
            if (kt + 2 < ntiles) load_v((kt + 2) * 64);

            f32x4 sc[4] = {};
            if (act) {
#pragma unroll
                for (int s = 0; s < 4; ++s) {
#pragma unroll
                    for (int t = 0; t < 4; ++t) {
                        bf16x8 bf = *reinterpret_cast<const bf16x8*>(
                            &KPg[(t * 16 + n16) * 128 + ((s * 32 + quad * 8) ^ xsw)]);
                        sc[t] = __builtin_amdgcn_mfma_f32_16x16x32_bf16(qf[s], bf, sc[t], 0, 0, 0);
                    }
                }
                if (kt == qt) {   // diagonal tile: causal mask
                    const int qbase = q0 + wg * 16 + quad * 4;
#pragma unroll
                    for (int t = 0; t < 4; ++t) {
                        int key = kt * 64 + t * 16 + n16;
#pragma unroll
                        for (int r = 0; r < 4; ++r)
                            if (key > qbase + r) sc[t][r] = -1e30f;
                    }
                }
            }

            __syncthreads();   // group's waves done reading K; P may overwrite

            if (act) {
#pragma unroll
                for (int r = 0; r < 4; ++r) {
                    float mx = fmaxf(fmaxf(sc[0][r], sc[1][r]), fmaxf(sc[2][r], sc[3][r]));
                    mx = fmaxf(mx, __shfl_xor(mx, 1));
                    mx = fmaxf(mx, __shfl_xor(mx, 2));
                    mx = fmaxf(mx, __shfl_xor(mx, 4));
                    mx = fmaxf(mx, __shfl_xor(mx, 8));
                    float mnew  = fmaxf(mrow[r], mx);
                    float alpha = __expf(mrow[r] - mnew);
                    float ls = 0.0f;
                    const int pr = quad * 4 + r;
#pragma unroll
                    for (int t = 0; t < 4; ++t) {
                        float p = __expf(sc[t][r] - mnew);
                        KPg[(wg * 16 + pr) * 64 + ((t * 16 + n16) ^ ((pr & 7) << 3))] = f2bf(p);
                        ls += p;
                    }
                    ls += __shfl_xor(ls, 1);
                    ls += __shfl_xor(ls, 2);
                    ls += __shfl_xor(ls, 4);
                    ls += __shfl_xor(ls, 8);
                    lrow[r] = lrow[r] * alpha + ls;
                    mrow[r] = mnew;
#pragma unroll
                    for (int nt = 0; nt < 8; ++nt) of[nt][r] *= alpha;
                }
                __threadfence_block();

#pragma unroll
                for (int s = 0; s < 2; ++s) {
                    bf16x8 af = *reinterpret_cast<const bf16x8*>(
                        &KPg[(wg * 16 + n16) * 64 + ((s * 32 + quad * 8) ^ xsw)]);
#pragma unroll
                    for (int nt = 0; nt < 8; ++nt) {
                        bf16x8 bf = *reinterpret_cast<const bf16x8*>(
                            &Vtg[(nt * 16 + n16) * 64 + ((s * 32 + quad * 8) ^ xsw)]);
                        of[nt] = __builtin_amdgcn_mfma_f32_16x16x32_bf16(af, bf, of[nt], 0, 0, 0);
                    }
                }
            }
        }

        // ---- merge the two groups' online-softmax partials, group 0 writes out
        __syncthreads();   // all PV reads done; LDS reusable as merge buffer
        if (grp == 1) {
            float* dst = mrg + ((size_t)(wg * 64 + lane)) * 40;
#pragma unroll
            for (int nt = 0; nt < 8; ++nt)
#pragma unroll
                for (int r = 0; r < 4; ++r) dst[nt * 4 + r] = of[nt][r];
#pragma unroll
            for (int r = 0; r < 4; ++r) { dst[32 + r] = mrow[r]; dst[36 + r] = lrow[r]; }
        }
        __syncthreads();
        if (grp == 0) {
            const float* src = mrg + ((size_t)(wg * 64 + lane)) * 40;
#pragma unroll
            for (int r = 0; r < 4; ++r) {
                const float mB = src[32 + r], lB = src[36 + r];
                const float m  = fmaxf(mrow[r], mB);
                const float a  = __expf(mrow[r] - m);
                const float b  = __expf(mB - m);
                const float inv = 1.0f / (lrow[r] * a + lB * b);
                u16* dst = ao + (size_t)(q0 + wg * 16 + quad * 4 + r) * (NH * HD) + h * HD + n16;
#pragma unroll
                for (int nt = 0; nt < 8; ++nt)
                    dst[nt * 16] = f2bf((of[nt][r] * a + src[nt * 4 + r] * b) * inv);
            }
        }
        __syncthreads();   // merge reads done before next half's staging
    }
}

// ---------------------------------------------------------------------------
// Fast-path workspace overlay (bytes), peak 92,274,688 (R11 layout):
//   hb     [2048][4096] bf16 @ 0          (16.8M)  A for gemm1; dead after
//   wqkv_b [6144][4096] bf16 @ 16,777,216 (50.3M)  B for gemm1; dead after
//   qb     [32][2048][128]   @ 67,108,864 (16.8M)  written by gemm1 epilogue
//   kb     [ 8][2048][128]   @ 83,886,080 ( 4.2M)
//   vb     [ 8][2048][128]   @ 88,080,384 ( 4.2M)  (ends exactly at 92,274,688)
//   wo_b   [4096][4096] bf16 @ 0          (33.5M)  after gemm1 (hb+wqkv dead)
//   ao     [2048][4096] bf16 @ 33,554,432 (16.8M)
//   rope table (1 MB, 2x 512KB cos/sin)  -> staged in d_out (33.5M f32);
//   gemm2 fully overwrites d_out afterwards, so this is free scratch.
// ---------------------------------------------------------------------------
extern "C" void kernel_launch(void* const* d_in, const int* in_sizes, int n_in,
                              void* d_out, int out_size, void* d_ws, size_t ws_size,
                              hipStream_t stream)
{
    const float* h   = (const float*)d_in[0];
    const int*   pos = (const int*)d_in[1];
    const float* wq  = (const float*)d_in[2];
    const float* wk  = (const float*)d_in[3];
    const float* wv  = (const float*)d_in[4];
    const float* wo  = (const float*)d_in[5];

    char* ws = (char*)d_ws;

    if (ws_size >= 92274688ull) {
        u16* hb     = (u16*)(ws);
        u16* wqkv_b = (u16*)(ws + 16777216);
        u16* qb     = (u16*)(ws + 67108864);
        u16* kb     = (u16*)(ws + 83886080);
        u16* vb     = (u16*)(ws + 88080384);
        u16* wo_b   = (u16*)(ws);
        u16* ao     = (u16*)(ws + 33554432);
        float* tab  = (float*)d_out;          // 1 MB scratch; gemm2 overwrites

        cvt_all<<<16384, 256, 0, stream>>>(h, wq, wk, wv, hb, wqkv_b);
        rope_table<<<512, 256, 0, stream>>>(pos, tab);
        gemm128<2><<<dim3(NQKV / 128, S_LEN / 128), 256, 0, stream>>>(
            hb, wqkv_b, nullptr, HID, 0, tab, qb, kb, vb);
        cvt_f32_bf16<<<8192, 256, 0, stream>>>(wo, wo_b, 2097152);
        attn_mfma<<<dim3(S_LEN / 128, NH), 512, 0, stream>>>(qb, kb, vb, ao);
        gemm128<0><<<dim3(HID / 128, S_LEN / 128), 256, 0, stream>>>(
            ao, wo_b, d_out, NH * HD, HID, nullptr, nullptr, nullptr, nullptr);
    } else {
        // ---- fallback (R3 layout, 64 MB)
        u16* qkv = (u16*)(ws);
        u16* qb  = (u16*)(ws + 25165824);
        u16* kb  = (u16*)(ws + 41943040);
        u16* vb  = (u16*)(ws + 46137344);
        u16* ao  = (u16*)(ws + 50331648);

        dim3 g1(NQKV / 64, S_LEN / 64);
        gemm_bt<true, true><<<g1, 256, 0, stream>>>(
            h, wq, NH * HD, wk, NH * HD + NKV * HD, wv, qkv, HID, NQKV);
        rope_kernel<<<S_LEN, 256, 0, stream>>>(qkv, pos, qb, kb, vb);
        attn_mfma<<<dim3(S_LEN / 128, NH), 512, 0, stream>>>(qb, kb, vb, ao);
        dim3 g2(HID / 64, S_LEN / 64);
        gemm_bt<false, false><<<g2, 256, 0, stream>>>(
            ao, wo, HID, wo, HID, wo, d_out, NH * HD, HID);
    }
}